// Round 5
// baseline (4170.530 us; speedup 1.0000x reference)
//
#include <hip/hip_runtime.h>

#define TT 1000
#define HH 512
#define G4 2048
#define NGRP 8
#define SPG 16        // seqs per group
#define SLOTS 32      // blocks per group
#define HCB 16        // h-cols per block (64 gate cols)

typedef __attribute__((ext_vector_type(8))) short bf16x8;
typedef __attribute__((ext_vector_type(4))) float f32x4;

__device__ __forceinline__ float sigm(float v) { return 1.0f / (1.0f + __expf(-v)); }
__device__ __forceinline__ float tanh_fast(float v) { return 2.0f / (1.0f + __expf(-2.0f * v)) - 1.0f; }

__device__ __forceinline__ unsigned short bf16rne(float f) {
    unsigned u = __float_as_uint(f);
    return (unsigned short)((u + 0x7fffu + ((u >> 16) & 1u)) >> 16);
}

// 256 blocks x 256 thr (1/CU). group g = bid&7 (XCD-local) owns seqs
// [g*16, g*16+16); slot = bid>>3 owns h-cols [slot*16,+16) -> 64 gate cols.
// W_hh in VGPRs. h(t) bf16 in LDS (swizzled). Exchange: register-shuffle
// pack -> per-wave u64 stores -> vmcnt -> barrier -> flag; out flush after
// flag (overlaps propagation); all-wave ballot poll, barrier-free refill.
__global__ __launch_bounds__(256, 1)
void lstm_mfma5(const float* __restrict__ x,     // [B][T][2]
                const float* __restrict__ wih,   // [2][4H]
                const float* __restrict__ whh,   // [H][4H]
                const float* __restrict__ bias,  // [4H]
                float* __restrict__ out,         // h [B][T][H] then c [B][T][H]
                float* ws)
{
    __shared__ short hsh[16 * 512];    // h(t) bf16, swizzled (16 KB)

    const int bid  = blockIdx.x;
    const int g    = bid & (NGRP - 1);
    const int slot = bid >> 3;
    const int tid  = threadIdx.x;
    const int wv   = tid >> 6;
    const int lane = tid & 63;
    const int col  = lane & 15;
    const int kb   = lane >> 4;            // k-subchunk / row-group
    const int q    = col & 3;              // gate id 0=f,1=i,2=o,3=g
    const int q1   = q & 1, q2 = q >> 1;
    const int cc   = col >> 2;             // col sub-index within wave
    const int hl   = wv * 4 + cc;          // block h-col 0..15
    const int gc   = q * 512 + slot * HCB + hl;   // global gate col
    const int rowSel = kb * 4 + q;         // this lane's owned seq row
    const int bSel   = g * SPG + rowSel;   // global batch index

    unsigned short* hbuf = (unsigned short*)ws;              // bf16 [2][128][512]
    unsigned* flags = (unsigned*)((char*)ws + 256 * 1024);   // [8][32] spaced 64B

    // zero hsh (t=0 state)
    for (int i = tid; i < 4096; i += 256) ((unsigned*)hsh)[i] = 0u;

    // ---- one-time: W_hh fragments straight into registers (64 VGPR) ----
    bf16x8 breg[16];
    #pragma unroll
    for (int kt = 0; kt < 16; ++kt) {
        bf16x8 f;
        #pragma unroll
        for (int j = 0; j < 8; ++j) {
            int k = kt * 32 + kb * 8 + j;
            f[j] = (short)bf16rne(whh[(size_t)k * G4 + gc]);
        }
        breg[kt] = f;
    }

    // per-lane gate constants (all 4 gates at this lane's h-col)
    float wA[4], wB[4], bb[4];
    #pragma unroll
    for (int j = 0; j < 4; ++j) {
        int gcj = j * 512 + slot * HCB + hl;
        wA[j] = wih[gcj]; wB[j] = wih[G4 + gcj]; bb[j] = bias[gcj];
    }

    const int arow = col;
    const int asw  = (arow & 7) << 3;
    const short* aBase = hsh + arow * 512;

    __syncthreads();

    float cst = 0.0f;
    const size_t OSZ = (size_t)128 * TT * HH;
    const float* xp = x + (size_t)bSel * TT * 2;
    float2 xv = *(const float2*)(xp);      // x(0) prefetched

    for (int t = 0; t < TT; ++t) {
        // ---- gates = h @ W_hh (K=512, MFMA, 2 acc chains) ----
        f32x4 acc0 = {0.f, 0.f, 0.f, 0.f};
        f32x4 acc1 = {0.f, 0.f, 0.f, 0.f};
        #pragma unroll
        for (int kt = 0; kt < 16; kt += 2) {
            int ka = (kt * 32 + kb * 8);
            bf16x8 a0 = *(const bf16x8*)(aBase + (ka ^ asw));
            acc0 = __builtin_amdgcn_mfma_f32_16x16x32_bf16(a0, breg[kt], acc0, 0, 0, 0);
            int kc = ((kt + 1) * 32 + kb * 8);
            bf16x8 a1 = *(const bf16x8*)(aBase + (kc ^ asw));
            acc1 = __builtin_amdgcn_mfma_f32_16x16x32_bf16(a1, breg[kt + 1], acc1, 0, 0, 0);
        }
        float v0 = acc0[0] + acc1[0], v1 = acc0[1] + acc1[1];
        float v2 = acc0[2] + acc1[2], v3 = acc0[3] + acc1[3];

        // ---- quad butterfly: lane ends with all 4 gates of row rowSel ----
        float vq = q2 ? (q1 ? v3 : v2) : (q1 ? v1 : v0);   // v[q]
        float s1 = q2 ? (q1 ? v2 : v3) : (q1 ? v0 : v1);   // v[q^1]
        float s2 = q2 ? (q1 ? v1 : v0) : (q1 ? v3 : v2);   // v[q^2]
        float s3 = q2 ? (q1 ? v0 : v1) : (q1 ? v2 : v3);   // v[q^3]
        float g1 = __shfl_xor(s1, 1);   // gate q^1 at row rowSel
        float g2 = __shfl_xor(s2, 2);   // gate q^2
        float g3 = __shfl_xor(s3, 3);   // gate q^3

        float fv = q2 ? (q1 ? g3 : g2) : (q1 ? g1 : vq);
        float iv = q2 ? (q1 ? g2 : g3) : (q1 ? vq : g1);
        float ov = q2 ? (q1 ? g1 : vq) : (q1 ? g3 : g2);
        float gv = q2 ? (q1 ? vq : g1) : (q1 ? g2 : g3);

        fv += xv.x * wA[0] + xv.y * wB[0] + bb[0];
        iv += xv.x * wA[1] + xv.y * wB[1] + bb[1];
        ov += xv.x * wA[2] + xv.y * wB[2] + bb[2];
        gv += xv.x * wA[3] + xv.y * wB[3] + bb[3];

        float c1 = sigm(fv) * cst + sigm(iv) * tanh_fast(gv);
        float h1 = sigm(ov) * tanh_fast(c1);
        cst = c1;

        // ---- register pack: cc==0 lanes gather cols hl..hl+3 of their row ----
        float hp1 = __shfl_xor(h1, 4);     // col cc^1
        float hp2 = __shfl_xor(h1, 8);     // col cc^2
        float hp3 = __shfl_xor(hp1, 8);    // col cc^3
        float cp1 = __shfl_xor(c1, 4);
        float cp2 = __shfl_xor(c1, 8);
        float cp3 = __shfl_xor(cp1, 8);

        if (t + 1 < TT) {
            // every wave stores its own 16 rows x 4 cols piece (16 u64)
            if (cc == 0) {
                unsigned long long pk =
                      (unsigned long long)bf16rne(h1)
                    | ((unsigned long long)bf16rne(hp1) << 16)
                    | ((unsigned long long)bf16rne(hp2) << 32)
                    | ((unsigned long long)bf16rne(hp3) << 48);
                size_t hidx = ((size_t)((t + 1) & 1) * 128 + bSel) * 512
                            + slot * HCB + wv * 4;
                __hip_atomic_store((unsigned long long*)(hbuf + hidx), pk,
                                   __ATOMIC_RELAXED, __HIP_MEMORY_SCOPE_AGENT);
            }
            asm volatile("s_waitcnt vmcnt(0)" ::: "memory");
            __syncthreads();
            if (tid == 0)
                __hip_atomic_store(&flags[(g * SLOTS + slot) * 16], (unsigned)(t + 1),
                                   __ATOMIC_RELAXED, __HIP_MEMORY_SCOPE_AGENT);
        }

        // ---- out flush from registers (overlaps flag propagation) ----
        if (cc == 0) {
            size_t oidx = ((size_t)bSel * TT + t) * HH + slot * HCB + wv * 4;
            float4 hq = {h1, hp1, hp2, hp3};
            float4 cq = {c1, cp1, cp2, cp3};
            *(float4*)(out + oidx) = hq;
            *(float4*)(out + OSZ + oidx) = cq;
        }

        if (t + 1 < TT) {
            xv = *(const float2*)(xp + 2 * (t + 1));   // prefetch x(t+1)

            // ---- all-wave ballot poll (no barrier; refill starts per-wave) ----
            const unsigned tgt = (unsigned)(t + 1);
            long gd = 0;
            for (;;) {
                unsigned fl = (lane < SLOTS)
                    ? __hip_atomic_load(&flags[(g * SLOTS + lane) * 16],
                                        __ATOMIC_RELAXED, __HIP_MEMORY_SCOPE_AGENT)
                    : tgt;
                if (__all(fl >= tgt)) break;
                __builtin_amdgcn_s_sleep(1);
                if (++gd > 50000000L) break;   // anti-hang escape
            }

            // ---- refill hsh with the group's h(t+1): 16 rows x 128 u64 ----
            const unsigned long long* src = (const unsigned long long*)
                (hbuf + ((size_t)((t + 1) & 1) * 128 + g * SPG) * 512);
            #pragma unroll
            for (int i = 0; i < 8; ++i) {
                int idx = i * 256 + tid;            // u64 index 0..2047
                unsigned long long d = __hip_atomic_load(src + idx,
                        __ATOMIC_RELAXED, __HIP_MEMORY_SCOPE_AGENT);
                int seq = idx >> 7;                 // 128 u64 per 512-bf16 row
                int k0  = (idx & 127) << 2;
                *(unsigned long long*)(hsh + seq * 512 + (k0 ^ ((seq & 7) << 3))) = d;
            }
            __syncthreads();
        }
    }
}

extern "C" void kernel_launch(void* const* d_in, const int* in_sizes, int n_in,
                              void* d_out, int out_size, void* d_ws, size_t ws_size,
                              hipStream_t stream) {
    const float* x    = (const float*)d_in[0];
    const float* wih  = (const float*)d_in[1];
    const float* whh  = (const float*)d_in[2];
    const float* bias = (const float*)d_in[3];
    float* out = (float*)d_out;
    float* ws  = (float*)d_ws;

    // zero the flag lines every launch (graph replay safe)
    hipMemsetAsync((char*)d_ws + 256 * 1024, 0, NGRP * SLOTS * 16 * sizeof(unsigned), stream);

    dim3 grid(NGRP * SLOTS), block(256);
    hipLaunchKernelGGL(lstm_mfma5, grid, block, 0, stream, x, wih, whh, bias, out, ws);
}